// Round 10
// baseline (1578.699 us; speedup 1.0000x reference)
//
#include <hip/hip_runtime.h>
#include <hip/hip_bf16.h>

typedef _Float16 f16x8 __attribute__((ext_vector_type(8)));
typedef _Float16 f16x4 __attribute__((ext_vector_type(4)));
typedef float f32x4 __attribute__((ext_vector_type(4)));
typedef float f32x16 __attribute__((ext_vector_type(16)));

#define MFMA16(A, B, C) __builtin_amdgcn_mfma_f32_16x16x32_f16((A), (B), (C), 0, 0, 0)
#define MFMA32(A, B, C) __builtin_amdgcn_mfma_f32_32x32x16_f16((A), (B), (C), 0, 0, 0)

#define DIMD 512
#define SEQ  8192
#define MTOT 16384  // 2*8192 rows
#define TILE_F16 65536   // 128KB per kv-tile: K 64x512 (64KB) + V^T 512x64 (64KB)

#define GLOAD16(gp, lp) __builtin_amdgcn_global_load_lds( \
    (const __attribute__((address_space(1))) void*)(gp),  \
    (__attribute__((address_space(3))) void*)(lp), 16, 0, 0)

#define LGKM0_BAR() do { \
    asm volatile("s_waitcnt lgkmcnt(0)" ::: "memory"); \
    __builtin_amdgcn_s_barrier(); \
    asm volatile("" ::: "memory"); } while (0)

// ---------------------------------------------------------------------------
// Projection GEMM (unchanged from r9): fp16 out; role-Q rows linear in Kh;
// role-K and role-V^T packed per 64-row kv tile (contiguous 128KB tiles).
// ---------------------------------------------------------------------------
__global__ __launch_bounds__(256) void proj_kernel(
    const float* __restrict__ x1,
    const float* __restrict__ Wk, const float* __restrict__ bk,
    const float* __restrict__ Wq, const float* __restrict__ bq,
    const float* __restrict__ Wv, const float* __restrict__ bv,
    _Float16* __restrict__ Kh, _Float16* __restrict__ pack)
{
    const int g = blockIdx.z;
    const float* W    = (g == 0) ? Wk : (g == 1) ? Wq : Wv;
    const float* bias = (g == 0) ? bk : (g == 1) ? bq : bv;

    const int m0 = blockIdx.x * 128;
    const int n0 = blockIdx.y * 128;
    const int t  = threadIdx.x;
    const int lane = t & 63;
    const int w  = t >> 6;
    const int wr = w >> 1, wc = w & 1;
    const int lr = lane & 15;
    const int lkg = lane >> 4;
    const int lk = lkg * 8;

    __shared__ _Float16 Ah[128][40];
    __shared__ _Float16 Bh[128][40];

    f32x4 acc[4][4] = {};

    const int sr  = t >> 1;
    const int skh = (t & 1) * 16;

    for (int k0 = 0; k0 < DIMD; k0 += 32) {
        const float* sa = x1 + (size_t)(m0 + sr) * DIMD + k0 + skh;
        const float* sb = W  + (size_t)(n0 + sr) * DIMD + k0 + skh;
        _Float16 ta[16], tb[16];
        #pragma unroll
        for (int i = 0; i < 4; i++) {
            f32x4 va = *(const f32x4*)(sa + i * 4);
            f32x4 vb = *(const f32x4*)(sb + i * 4);
            #pragma unroll
            for (int u = 0; u < 4; u++) {
                ta[i * 4 + u] = (_Float16)va[u];
                tb[i * 4 + u] = (_Float16)vb[u];
            }
        }
        __syncthreads();
        *(f16x8*)&Ah[sr][skh]     = *(f16x8*)&ta[0];
        *(f16x8*)&Ah[sr][skh + 8] = *(f16x8*)&ta[8];
        *(f16x8*)&Bh[sr][skh]     = *(f16x8*)&tb[0];
        *(f16x8*)&Bh[sr][skh + 8] = *(f16x8*)&tb[8];
        __syncthreads();

        f16x8 af[4], bf[4];
        #pragma unroll
        for (int i = 0; i < 4; i++) af[i] = *(const f16x8*)&Ah[wr * 64 + i * 16 + lr][lk];
        #pragma unroll
        for (int j = 0; j < 4; j++) bf[j] = *(const f16x8*)&Bh[wc * 64 + j * 16 + lr][lk];
        #pragma unroll
        for (int i = 0; i < 4; i++)
            #pragma unroll
            for (int j = 0; j < 4; j++)
                acc[i][j] = MFMA16(af[i], bf[j], acc[i][j]);
    }

    const int col0 = n0 + wc * 64;
    const int row0 = m0 + wr * 64;
    #pragma unroll
    for (int j = 0; j < 4; j++) {
        float bval = bias[col0 + j * 16 + lr];
        #pragma unroll
        for (int i = 0; i < 4; i++) {
            #pragma unroll
            for (int jj = 0; jj < 4; jj++) {
                int mrow = row0 + i * 16 + lkg * 4 + jj;
                int e    = col0 + j * 16 + lr;
                float val = acc[i][j][jj] + bval;
                _Float16 hv = (_Float16)val;
                const int batch = mrow >> 13;
                const int s     = mrow & 8191;
                if (g == 0) {
                    Kh[(size_t)mrow * DIMD + e] = hv;
                } else if (g == 1) {
                    pack[((size_t)(batch * 128 + (s >> 6))) * TILE_F16
                         + (size_t)(s & 63) * DIMD + e] = hv;
                } else {
                    pack[((size_t)(batch * 128 + (s >> 6))) * TILE_F16
                         + 32768 + (size_t)e * 64 + (s & 63)] = hv;
                }
            }
        }
    }
}

// ---------------------------------------------------------------------------
// Flash attention v10: XCD-owned 4MB chunk + self-reuse.
// 8 chunks = (batch 2 x kv-quarter 4), one per physical XCD (XCC_ID claim,
// r8 mechanism + scavenge fallback). Each XCD's 32 blocks take 256 q-rows
// each and sweep the chunk's 32 packed tiles TWICE (2 panels of 128 rows,
// serpentine order: panel 1 runs tiles in reverse, starting on panel 0's
// hot tail). Entire per-XCD working set = one contiguous 4MB region = its
// L2 -> reuse is capacity-guaranteed AND drift-immune AND set-uniform
// (packed layout fixed r8's 16KB-stride set aliasing).
// Q loads / Opart / Ml stores nontemporal to protect residency.
// ---------------------------------------------------------------------------
__global__ __launch_bounds__(512, 2) void flash_claim(
    const _Float16* __restrict__ Kh,    // role-Q rows (linear)
    const _Float16* __restrict__ pack,  // packed K/V^T tiles
    _Float16* __restrict__ Opart,       // [4][MTOT][512]
    float* __restrict__ Ml,             // [4][MTOT][2]
    int* __restrict__ ctrl)             // [0..7] cnt, [8] scan, [16..271] flags
{
    const int t    = threadIdx.x;
    const int lane = t & 63;
    const int w    = t >> 6;          // 0..7
    const int q31  = lane & 31;
    const int h    = lane >> 5;       // 0/1
    const int mg   = w >> 1;          // m-group (32 rows each)
    const int kh   = w & 1;           // kv-half for QK^T

    __shared__ _Float16 Klds[64][512];
    __shared__ _Float16 Vlds[512][64];
    __shared__ _Float16 Plds[128][64];
    __shared__ float Mbuf[8][32];
    __shared__ float Sbuf[8][32];
    __shared__ float Scl[128];
    __shared__ int NeedR;
    __shared__ int sh_slot;

    // ---- claim a slot (chunk = this XCD's; 32 q-subranges per chunk) ----
    if (t == 0) {
        int xcc;
        asm volatile("s_getreg_b32 %0, hwreg(HW_REG_XCC_ID)" : "=s"(xcc));
        xcc &= 7;
        int s = __hip_atomic_fetch_add(&ctrl[xcc], 1, __ATOMIC_RELAXED,
                                       __HIP_MEMORY_SCOPE_AGENT);
        int slot = -1;
        if (s < 32) {
            int p = xcc * 32 + s;
            int old = __hip_atomic_exchange(&ctrl[16 + p], 1, __ATOMIC_RELAXED,
                                            __HIP_MEMORY_SCOPE_AGENT);
            if (old == 0) slot = p;
        }
        while (slot < 0) {   // anomalous placement: scavenge
            int g = __hip_atomic_fetch_add(&ctrl[8], 1, __ATOMIC_RELAXED,
                                           __HIP_MEMORY_SCOPE_AGENT) & 255;
            int old = __hip_atomic_exchange(&ctrl[16 + g], 1, __ATOMIC_RELAXED,
                                            __HIP_MEMORY_SCOPE_AGENT);
            if (old == 0) slot = g;
        }
        sh_slot = slot;
        NeedR = 0;
    }
    __syncthreads();
    const int slot  = sh_slot;
    const int chunk = slot >> 5;        // 0..7
    const int batch = chunk >> 2;       // 0..1
    const int kvq   = chunk & 3;        // kv-quarter
    const int qslot = slot & 31;        // q-subrange within batch

    const size_t packrow = (size_t)batch * 128 + kvq * 32;  // 32 tiles per chunk

    #define STAGE_K(ti)                                                        \
    {                                                                          \
        const char* tb = (const char*)(pack + (packrow + (ti)) * TILE_F16);    \
        _Pragma("unroll")                                                      \
        for (int i = 0; i < 8; i++) {                                          \
            const int r = w * 8 + i;                                           \
            GLOAD16(tb + r * 1024 + ((lane ^ (r & 15)) << 4),                  \
                    (char*)&Klds[r][0]);                                       \
        }                                                                      \
    }
    #define STAGE_V(ti)                                                        \
    {                                                                          \
        const char* tb = (const char*)(pack + (packrow + (ti)) * TILE_F16)     \
                         + 65536;                                              \
        _Pragma("unroll")                                                      \
        for (int i = 0; i < 8; i++) {                                          \
            const int D0 = (w * 8 + i) * 8;                                    \
            const int dr = D0 + (lane >> 3);                                   \
            GLOAD16(tb + dr * 128 + (((lane & 7) ^ (dr & 7)) << 4),            \
                    (char*)&Vlds[D0][0]);                                      \
        }                                                                      \
    }

    STAGE_K(0);
    STAGE_V(0);

    for (int p = 0; p < 2; ++p) {
        const int R0 = batch * SEQ + qslot * 256 + p * 128;

        // role-Q fragments (nontemporal)
        const int qrow = R0 + mg * 32 + q31;
        f16x8 qf[32];
        #pragma unroll
        for (int ks = 0; ks < 32; ks++)
            qf[ks] = __builtin_nontemporal_load(
                (const f16x8*)(Kh + (size_t)qrow * DIMD + ks * 16 + h * 8));

        f32x16 Oacc[4][2] = {};
        float m_ = -1e30f, l_ = 0.f;

        for (int j = 0; j < 32; ++j) {
            const int it = (p & 1) ? (31 - j) : j;        // serpentine
            // next tile (serpentine across the panel boundary)
            int np = p, nj = j + 1;
            if (nj == 32) { np = p + 1; nj = 0; }
            const bool hasNext = (np < 2);
            const int itn = hasNext ? ((np & 1) ? (31 - nj) : nj) : it;
            const bool doStage = hasNext && (itn != it);  // boundary: same tile

            // TOP sync: K(t) and V(t) resident.
            asm volatile("s_waitcnt vmcnt(0)" ::: "memory");
            __builtin_amdgcn_s_barrier();
            asm volatile("" ::: "memory");

            // ---- QK^T: S^T[kv 32 (half kh)][q 32 (group mg)] ----
            f32x16 sT = {};
            const int krow = kh * 32 + q31;
            #pragma unroll
            for (int ks = 0; ks < 32; ks++) {
                const int ch = ((2 * ks + h) ^ (lane & 15)) << 4;
                f16x8 af = *(const f16x8*)((const char*)&Klds[krow][0] + ch);
                sT = MFMA32(af, qf[ks], sT);
            }

            // ---- softmax part 1 ----
            float mx = sT[0];
            #pragma unroll
            for (int r = 1; r < 16; r++) mx = fmaxf(mx, sT[r]);
            mx = fmaxf(mx, __shfl_xor(mx, 32, 64));
            if (lane < 32) Mbuf[w][lane] = mx;

            LGKM0_BAR();   // barrier A: Mbuf visible; all K reads done

            if (doStage) STAGE_K(itn);

            // ---- softmax part 2: defer-max, exp, partial sum, P write ----
            float pm = fmaxf(mx, Mbuf[w ^ 1][q31]);
            float scale = 1.f;
            if (pm > m_ + 8.f) { scale = __expf(m_ - pm); m_ = pm; }
            float ps = 0.f;
            f16x4 pq[4];
            #pragma unroll
            for (int r = 0; r < 16; r++) {
                float pv = __expf(sT[r] - m_);
                ps += pv;
                pq[r >> 2][r & 3] = (_Float16)pv;
            }
            ps += __shfl_xor(ps, 32, 64);
            if (lane < 32) {
                Sbuf[w][lane] = ps;
                if (kh == 0) Scl[mg * 32 + lane] = scale;
            }
            if (__any(scale != 1.f) && lane == 0) NeedR = 1;
            #pragma unroll
            for (int rq = 0; rq < 4; rq++) {
                int s  = kh * 8 + 2 * rq + h;
                int sp = s ^ (lane & 15);
                *(f16x4*)((char*)&Plds[mg * 32 + q31][0] + sp * 8) = pq[rq];
            }

            LGKM0_BAR();   // barrier B: P/Sbuf/Scl visible (V resident)

            // ---- l update + conditional O rescale ----
            l_ = l_ * scale + (ps + Sbuf[w ^ 1][q31]);
            if (NeedR) {
                #pragma unroll
                for (int m2 = 0; m2 < 4; m2++) {
                    #pragma unroll
                    for (int rq = 0; rq < 4; rq++) {
                        f32x4 s4 = *(const f32x4*)&Scl[m2 * 32 + rq * 8 + 4 * h];
                        #pragma unroll
                        for (int n = 0; n < 2; n++)
                            #pragma unroll
                            for (int e = 0; e < 4; e++)
                                Oacc[m2][n][rq * 4 + e] *= s4[e];
                    }
                }
            }

            // ---- PV ----
            #pragma unroll
            for (int ks = 0; ks < 4; ks++) {
                f16x8 vb[2];
                #pragma unroll
                for (int n = 0; n < 2; n++) {
                    const int dd = w * 64 + n * 32 + q31;
                    const int ch = ((2 * ks + h) ^ (dd & 7)) << 4;
                    vb[n] = *(const f16x8*)((const char*)&Vlds[dd][0] + ch);
                }
                #pragma unroll
                for (int m2 = 0; m2 < 4; m2++) {
                    const char* prow = (const char*)&Plds[m2 * 32 + q31][0];
                    const int s0 = ((4 * ks + 2 * h)     ^ (lane & 15)) * 8;
                    const int s1 = ((4 * ks + 2 * h + 1) ^ (lane & 15)) * 8;
                    f16x4 a0 = *(const f16x4*)(prow + s0);
                    f16x4 a1 = *(const f16x4*)(prow + s1);
                    f16x8 pa;
                    #pragma unroll
                    for (int e = 0; e < 4; e++) { pa[e] = a0[e]; pa[e + 4] = a1[e]; }
                    #pragma unroll
                    for (int n = 0; n < 2; n++)
                        Oacc[m2][n] = MFMA32(pa, vb[n], Oacc[m2][n]);
                }
            }

            LGKM0_BAR();   // barrier C: all V/P reads done
            if (t == 0) NeedR = 0;
            if (doStage) STAGE_V(itn);
        }

        // ---- panel epilogue: share 1/l, write Ml + Opart (nontemporal) ----
        if (kh == 0 && lane < 32) {
            Scl[mg * 32 + lane] = 1.f / l_;
            int R = R0 + mg * 32 + lane;
            __builtin_nontemporal_store(m_, &Ml[((size_t)kvq * MTOT + R) * 2]);
            __builtin_nontemporal_store(l_, &Ml[((size_t)kvq * MTOT + R) * 2 + 1]);
        }
        LGKM0_BAR();

        #pragma unroll
        for (int m2 = 0; m2 < 4; m2++) {
            #pragma unroll
            for (int rq = 0; rq < 4; rq++) {
                f32x4 li = *(const f32x4*)&Scl[m2 * 32 + rq * 8 + 4 * h];
                #pragma unroll
                for (int e = 0; e < 4; e++) {
                    int row = R0 + m2 * 32 + rq * 8 + 4 * h + e;
                    #pragma unroll
                    for (int n = 0; n < 2; n++) {
                        int d = w * 64 + n * 32 + q31;
                        float val = Oacc[m2][n][rq * 4 + e] * li[e];
                        __builtin_nontemporal_store(
                            (_Float16)val,
                            &Opart[((size_t)kvq * MTOT + row) * DIMD + d]);
                    }
                }
            }
        }
        LGKM0_BAR();   // Scl/Plds safe for next panel
    }
    #undef STAGE_K
    #undef STAGE_V
}

// ---------------------------------------------------------------------------
// Combine 4 kv-quarter partials: out = sum a_h*O_h, a_h = e^{m_h-M} l_h / Z
// ---------------------------------------------------------------------------
__global__ __launch_bounds__(256) void combine_kernel(
    const _Float16* __restrict__ Opart, const float* __restrict__ Ml,
    float* __restrict__ out)
{
    size_t idx = (size_t)blockIdx.x * 256 + threadIdx.x;
    size_t e0 = idx * 8;
    int R = (int)(e0 >> 9);
    float m[4], l[4];
    float M = -1e30f;
    #pragma unroll
    for (int hh = 0; hh < 4; hh++) {
        m[hh] = Ml[((size_t)hh * MTOT + R) * 2];
        l[hh] = Ml[((size_t)hh * MTOT + R) * 2 + 1];
        M = fmaxf(M, m[hh]);
    }
    float a[4], Z = 0.f;
    #pragma unroll
    for (int hh = 0; hh < 4; hh++) { a[hh] = __expf(m[hh] - M) * l[hh]; Z += a[hh]; }
    float inv = 1.f / Z;
    float acc[8] = {};
    #pragma unroll
    for (int hh = 0; hh < 4; hh++) {
        f16x8 o = __builtin_nontemporal_load(
            (const f16x8*)(Opart + (size_t)hh * MTOT * DIMD + e0));
        float ah = a[hh] * inv;
        #pragma unroll
        for (int u = 0; u < 8; u++) acc[u] += ah * (float)o[u];
    }
    f32x4 r0, r1;
    #pragma unroll
    for (int u = 0; u < 4; u++) { r0[u] = acc[u]; r1[u] = acc[u + 4]; }
    *(f32x4*)(out + e0) = r0;
    *(f32x4*)(out + e0 + 4) = r1;
}

extern "C" void kernel_launch(void* const* d_in, const int* in_sizes, int n_in,
                              void* d_out, int out_size, void* d_ws, size_t ws_size,
                              hipStream_t stream) {
    (void)in_sizes; (void)n_in; (void)out_size; (void)ws_size;
    const float* x1 = (const float*)d_in[0];
    const float* Wk = (const float*)d_in[1];
    const float* bk = (const float*)d_in[2];
    const float* Wq = (const float*)d_in[3];
    const float* bq = (const float*)d_in[4];
    const float* Wv = (const float*)d_in[5];
    const float* bv = (const float*)d_in[6];
    float* out = (float*)d_out;

    _Float16* Kh   = (_Float16*)d_ws;                          // 16 MB
    _Float16* pack = Kh + (size_t)MTOT * DIMD;                 // 32 MB packed

    const size_t base = (size_t)MTOT * DIMD * 2 * 3;           // 48 MB
    const size_t opart_slice = (size_t)MTOT * DIMD * sizeof(_Float16);  // 16 MB
    _Float16* Opart = (_Float16*)((char*)d_ws + base);                   // 64 MB
    float*    Ml    = (float*)((char*)d_ws + base + 4 * opart_slice);    // 512 KB
    int*      ctrl  = (int*)((char*)d_ws + base + 4 * opart_slice
                             + (size_t)4 * MTOT * 2 * sizeof(float));

    // mask output: 16 zero floats after the attention output
    hipMemsetAsync((char*)d_out + (size_t)MTOT * DIMD * sizeof(float), 0, 64, stream);
    // zero claim state each launch (graph-safe)
    hipMemsetAsync(ctrl, 0, (16 + 256) * sizeof(int), stream);

    dim3 pg(128, 4, 3);
    proj_kernel<<<pg, 256, 0, stream>>>(x1, Wk, bk, Wq, bq, Wv, bv, Kh, pack);

    flash_claim<<<dim3(256), 512, 0, stream>>>(Kh, pack, Opart, Ml, ctrl);
    combine_kernel<<<4096, 256, 0, stream>>>(Opart, Ml, out);
}